// Round 2
// baseline (325.179 us; speedup 1.0000x reference)
//
#include <hip/hip_runtime.h>

#define B_SZ 1024
#define H_SZ 2048
#define E_SZ 1024

typedef float  f32x4 __attribute__((ext_vector_type(4)));
typedef short  s16x8 __attribute__((ext_vector_type(8)));

__device__ __forceinline__ unsigned short f2bf(float f) {
    unsigned u = __float_as_uint(f);
    u = u + 0x7fffu + ((u >> 16) & 1u);   // RNE
    return (unsigned short)(u >> 16);
}
__device__ __forceinline__ float bf2f(unsigned short s) {
    return __uint_as_float(((unsigned)s) << 16);
}
__device__ __forceinline__ float sigm(float v) {
    return 1.0f / (1.0f + __expf(-v));
}

__device__ __forceinline__ void gll(const unsigned short* g, unsigned short* l) {
    __builtin_amdgcn_global_load_lds(
        (const __attribute__((address_space(1))) unsigned int*)g,
        (__attribute__((address_space(3))) unsigned int*)l, 16, 0, 0);
}

// ---------------------------------------------------------------- cast pass
struct CastArgs {
    const float*    src[11];
    unsigned short* dst[11];
    int             n[11];
};

__global__ __launch_bounds__(256) void cast_kernel(CastArgs a) {
    const int arr = blockIdx.y;
    const int n = a.n[arr];
    const float* __restrict__ s = a.src[arr];
    unsigned short* __restrict__ d = a.dst[arr];
    const int stride = gridDim.x * 256 * 4;
    for (int i = (blockIdx.x * 256 + threadIdx.x) * 4; i < n; i += stride) {
        float4 v = *(const float4*)(s + i);
        ushort4 o;
        o.x = f2bf(v.x); o.y = f2bf(v.y); o.z = f2bf(v.z); o.w = f2bf(v.w);
        *(ushort4*)(d + i) = o;
    }
}

// ----------------------------------------- bf16 GEMM core, BK=64 + swizzle
// (retained for the y split-K kernel)
__device__ __forceinline__ void gemm_accum64(
    const unsigned short* __restrict__ A,
    const unsigned short* __restrict__ W,
    int ld, int kLen, int m0, int n0,
    unsigned short* lA, unsigned short* lB,
    f32x4 acc[4][4], int t)
{
    const int lane = t & 63;
    const int w    = t >> 6;
    const int wr   = (w >> 1) << 6;
    const int wc   = (w & 1) << 6;
    const int lr   = lane & 15;
    const int q4   = lane >> 4;

    const int srow = t >> 3;
    const int scol = ((t & 7) ^ (srow & 7)) << 3;
    const unsigned short* gA = A + (size_t)(m0 + srow) * ld + scol;
    const unsigned short* gB = W + (size_t)(n0 + srow) * ld + scol;
    const size_t st32 = (size_t)32 * ld;

    const int cb0 = ((q4    ) ^ (lr & 7)) << 3;
    const int cb1 = ((4 + q4) ^ (lr & 7)) << 3;

    for (int k0 = 0; k0 < kLen; k0 += 64) {
#pragma unroll
        for (int p = 0; p < 4; ++p)
            gll(gA + k0 + p * st32, lA + (t + 256 * p) * 8);
#pragma unroll
        for (int p = 0; p < 4; ++p)
            gll(gB + k0 + p * st32, lB + (t + 256 * p) * 8);
        __syncthreads();

#pragma unroll
        for (int ks = 0; ks < 2; ++ks) {
            const int cb = ks ? cb1 : cb0;
            s16x8 af[4], bfr[4];
#pragma unroll
            for (int i = 0; i < 4; ++i)
                af[i] = *(const s16x8*)(lA + (wr + i * 16 + lr) * 64 + cb);
#pragma unroll
            for (int j = 0; j < 4; ++j)
                bfr[j] = *(const s16x8*)(lB + (wc + j * 16 + lr) * 64 + cb);
#pragma unroll
            for (int i = 0; i < 4; ++i)
#pragma unroll
                for (int j = 0; j < 4; ++j)
                    acc[i][j] = __builtin_amdgcn_mfma_f32_16x16x32_bf16(
                        af[i], bfr[j], acc[i][j], 0, 0, 0);
        }
        __syncthreads();
    }
}

// -------------------------------------------------------------- gate GEMMs
// 96-phase half-tile ring pipeline. BM=256 x BN=128 over M=1024, N=4*2048
// -> 256 blocks = 1/CU, 512 thr = 8 waves (4M x 2N), 64x64 per wave.
// K unified: halves 0..31 = E (X@Wx^T), 32..95 = H (H@Wh^T); half h = K cols
// [32h, 32h+32). LDS ring: 6 slots x (A 16KB + B 8KB) = 144KB.
// Phase p: {ds_read slot p%6; gll half p+4 -> slot (p+4)%6; vmcnt(9);
// barrier; lgkm(0); 16 MFMA}. ONE barrier/phase: the barrier region spans
// MFMA(p-1)+ds_read(p) so waves overlap the two pipes. vmcnt(9) leaves
// halves p+2..p+4 in flight (3-phase ~1000cy HBM cover); never drains.
__global__ __launch_bounds__(512, 2) void gates8_kernel(
    const unsigned short* __restrict__ Xb,
    const unsigned short* __restrict__ Hb,
    const unsigned short* __restrict__ Wxb,
    const unsigned short* __restrict__ Whb,
    const float* __restrict__ bi, const float* __restrict__ bg,
    const float* __restrict__ bff, const float* __restrict__ bo,
    unsigned short* __restrict__ Z)
{
    __shared__ unsigned short lA[6 * 8192];   // slot: [256 rows][32 cols] swz
    __shared__ unsigned short lB[6 * 4096];   // slot: [128 rows][32 cols] swz

    const int t   = threadIdx.x;
    const int b   = blockIdx.x;
    const int xcd = b & 7;
    const int i_  = b >> 3;                  // 0..31 within XCD
    const int ntg = xcd * 8 + (i_ >> 2);     // 0..63 gate-major col tile
    const int m0  = (i_ & 3) * 256;
    const int n0g = ntg * 128;
    const int q   = n0g >> 11;               // gate index
    const int nl  = n0g & (H_SZ - 1);        // col base within gate

    // staging: LDS chunk c=t(+512) -> (row=c>>2, pos=c&3); source col-block
    // pre-swizzled pos ^ ((row>>1)&3); read applies same XOR -> 2-way banks.
    const int sc = (((t & 3) ^ ((t >> 3) & 3)) << 3);
    const int rA = t >> 2;                               // 0..127
    const unsigned short* AE0 = Xb + (size_t)(m0 + rA) * E_SZ + sc;
    const unsigned short* AE1 = AE0 + (size_t)128 * E_SZ;
    const unsigned short* AH0 = Hb + (size_t)(m0 + rA) * H_SZ + sc;
    const unsigned short* AH1 = AH0 + (size_t)128 * H_SZ;
    const unsigned short* BEp = Wxb + (size_t)q * H_SZ * E_SZ + (size_t)(nl + rA) * E_SZ + sc;
    const unsigned short* BHp = Whb + (size_t)q * H_SZ * H_SZ + (size_t)(nl + rA) * H_SZ + sc;

    auto stage = [&](int h, unsigned short* dA, unsigned short* dB) {
        if (h < 32) {
            const int k = h * 32;
            gll(AE0 + k, dA); gll(AE1 + k, dA + 4096); gll(BEp + k, dB);
        } else {
            const int k = (h - 32) * 32;
            gll(AH0 + k, dA); gll(AH1 + k, dA + 4096); gll(BHp + k, dB);
        }
    };

    // fragment read offsets (swizzled), fixed per thread
    const int lane = t & 63;
    const int w    = t >> 6;
    const int wr   = (w >> 1) << 6;          // 0,64,128,192
    const int wc   = (w & 1) << 6;           // 0,64
    const int lr   = lane & 15;
    const int q4   = lane >> 4;
    int offA[4], offB[4];
#pragma unroll
    for (int i = 0; i < 4; ++i) {
        const int ra = wr + i * 16 + lr;
        offA[i] = ra * 32 + ((q4 ^ ((ra >> 1) & 3)) << 3);
        const int rb = wc + i * 16 + lr;
        offB[i] = rb * 32 + ((q4 ^ ((rb >> 1) & 3)) << 3);
    }

    f32x4 acc[4][4] = {};

    // prologue: halves 0..3 (12 gll). vmcnt(9) -> half 0 landed; barrier.
    stage(0, lA + 0 * 8192 + t * 8, lB + 0 * 4096 + t * 8);
    stage(1, lA + 1 * 8192 + t * 8, lB + 1 * 4096 + t * 8);
    stage(2, lA + 2 * 8192 + t * 8, lB + 2 * 4096 + t * 8);
    stage(3, lA + 3 * 8192 + t * 8, lB + 3 * 4096 + t * 8);
    asm volatile("s_waitcnt vmcnt(9)" ::: "memory");
    asm volatile("s_barrier" ::: "memory");

#define PHASE(P_, S, SN, WAITN, DO_STAGE)                                 \
  {                                                                       \
    const unsigned short* pA = lA + (S) * 8192;                           \
    const unsigned short* pB = lB + (S) * 4096;                           \
    s16x8 af[4], bv[4];                                                   \
    af[0] = *(const s16x8*)(pA + offA[0]);                                \
    af[1] = *(const s16x8*)(pA + offA[1]);                                \
    af[2] = *(const s16x8*)(pA + offA[2]);                                \
    af[3] = *(const s16x8*)(pA + offA[3]);                                \
    bv[0] = *(const s16x8*)(pB + offB[0]);                                \
    bv[1] = *(const s16x8*)(pB + offB[1]);                                \
    bv[2] = *(const s16x8*)(pB + offB[2]);                                \
    bv[3] = *(const s16x8*)(pB + offB[3]);                                \
    if (DO_STAGE) stage((P_) + 4, lA + (SN) * 8192 + t * 8,               \
                        lB + (SN) * 4096 + t * 8);                        \
    asm volatile("s_waitcnt vmcnt(" WAITN ")" ::: "memory");              \
    asm volatile("s_barrier" ::: "memory");                               \
    asm volatile("s_waitcnt lgkmcnt(0)" ::: "memory");                    \
    __builtin_amdgcn_sched_barrier(0);                                    \
    __builtin_amdgcn_s_setprio(1);                                        \
    _Pragma("unroll") for (int i2 = 0; i2 < 4; ++i2)                      \
      _Pragma("unroll") for (int j2 = 0; j2 < 4; ++j2)                    \
        acc[i2][j2] = __builtin_amdgcn_mfma_f32_16x16x32_bf16(            \
            af[i2], bv[j2], acc[i2][j2], 0, 0, 0);                        \
    __builtin_amdgcn_s_setprio(0);                                        \
  }

    for (int g = 0; g < 15; ++g) {
        const int h0 = g * 6;
        PHASE(h0 + 0, 0, 4, "9", true);
        PHASE(h0 + 1, 1, 5, "9", true);
        PHASE(h0 + 2, 2, 0, "9", true);
        PHASE(h0 + 3, 3, 1, "9", true);
        PHASE(h0 + 4, 4, 2, "9", true);
        PHASE(h0 + 5, 5, 3, "9", true);
    }
    // tail: halves 90..95 (last stages: h=94 at p=90, h=95 at p=91)
    PHASE(90, 0, 4, "9", true);
    PHASE(91, 1, 5, "9", true);
    PHASE(92, 2, 0, "6", false);
    PHASE(93, 3, 1, "3", false);
    PHASE(94, 4, 2, "0", false);
    PHASE(95, 5, 3, "0", false);
#undef PHASE

    // epilogue: bias + activation, write bf16 Z
    const float* bias = (q == 0) ? bi : (q == 1) ? bg : (q == 2) ? bff : bo;
    unsigned short* Zq = Z + (size_t)q * B_SZ * H_SZ;
    const int rq = (lane >> 4) << 2;
#pragma unroll
    for (int i = 0; i < 4; ++i) {
#pragma unroll
        for (int j = 0; j < 4; ++j) {
            const int n = nl + wc + j * 16 + lr;
            const float bvv = bias[n];
#pragma unroll
            for (int r = 0; r < 4; ++r) {
                const int m = m0 + wr + i * 16 + rq + r;
                const float v = acc[i][j][r] + bvv;
                const float a = (q == 1) ? tanhf(v) : sigm(v);
                Zq[(size_t)m * H_SZ + n] = f2bf(a);
            }
        }
    }
}

// ------------------------------------------------------------ cell update
__global__ __launch_bounds__(256) void cell_kernel(
    const unsigned short* __restrict__ Z, const float* __restrict__ c,
    float* __restrict__ c_out, float* __restrict__ h_out,
    unsigned short* __restrict__ HnB)
{
    const size_t BH = (size_t)B_SZ * H_SZ;
    const int idx = (blockIdx.x * 256 + threadIdx.x) * 4;
    ushort4 iu = *(const ushort4*)(Z + idx);
    ushort4 gu = *(const ushort4*)(Z + BH + idx);
    ushort4 fu = *(const ushort4*)(Z + 2 * BH + idx);
    ushort4 ou = *(const ushort4*)(Z + 3 * BH + idx);
    float4 cv = *(const float4*)(c + idx);

    float cn[4], hn[4];
    cn[0] = bf2f(fu.x) * cv.x + bf2f(iu.x) * bf2f(gu.x);
    cn[1] = bf2f(fu.y) * cv.y + bf2f(iu.y) * bf2f(gu.y);
    cn[2] = bf2f(fu.z) * cv.z + bf2f(iu.z) * bf2f(gu.z);
    cn[3] = bf2f(fu.w) * cv.w + bf2f(iu.w) * bf2f(gu.w);
    hn[0] = bf2f(ou.x) * cn[0];
    hn[1] = bf2f(ou.y) * cn[1];
    hn[2] = bf2f(ou.z) * cn[2];
    hn[3] = bf2f(ou.w) * cn[3];

    *(float4*)(c_out + idx) = make_float4(cn[0], cn[1], cn[2], cn[3]);
    *(float4*)(h_out + idx) = make_float4(hn[0], hn[1], hn[2], hn[3]);
    ushort4 hb;
    hb.x = f2bf(hn[0]); hb.y = f2bf(hn[1]); hb.z = f2bf(hn[2]); hb.w = f2bf(hn[3]);
    *(ushort4*)(HnB + idx) = hb;
}

// ---------------------------------------------------- y GEMM, split-K by 4
__global__ __launch_bounds__(256) void y_split_kernel(
    const unsigned short* __restrict__ Hn,
    const unsigned short* __restrict__ Wy,
    float* __restrict__ part)
{
    __shared__ unsigned short lA[128 * 64];
    __shared__ unsigned short lB[128 * 64];
    const int t   = threadIdx.x;
    const int b   = blockIdx.x;
    const int xcd = b & 7;
    const int i_  = b >> 3;                 // 0..31 within XCD
    const int ns  = xcd * 4 + (i_ >> 3);    // 0..31: (n-tile, split)
    const int m0  = (i_ & 7) * 128;
    const int n0  = (ns >> 2) * 128;
    const int s   = ns & 3;

    f32x4 acc[4][4] = {};
    gemm_accum64(Hn + s * 512, Wy + s * 512, H_SZ, 512, m0, n0, lA, lB, acc, t);

    const int lane = t & 63, w = t >> 6;
    const int wr = (w >> 1) << 6, wc = (w & 1) << 6;
    const int lr = lane & 15, rq = (lane >> 4) << 2;
    float* P = part + (size_t)s * B_SZ * E_SZ;
#pragma unroll
    for (int i = 0; i < 4; ++i) {
#pragma unroll
        for (int j = 0; j < 4; ++j) {
            const int n = n0 + wc + j * 16 + lr;
#pragma unroll
            for (int r = 0; r < 4; ++r) {
                const int m = m0 + wr + i * 16 + rq + r;
                P[(size_t)m * E_SZ + n] = acc[i][j][r];
            }
        }
    }
}

__global__ __launch_bounds__(256) void y_reduce_kernel(
    const float* __restrict__ part, const float* __restrict__ by,
    float* __restrict__ yout)
{
    const size_t BE = (size_t)B_SZ * E_SZ;
    const int idx = (blockIdx.x * 256 + threadIdx.x) * 4;
    float4 a = *(const float4*)(part + idx);
    float4 b2 = *(const float4*)(part + BE + idx);
    float4 c2 = *(const float4*)(part + 2 * BE + idx);
    float4 d2 = *(const float4*)(part + 3 * BE + idx);
    const int col = idx & (E_SZ - 1);
    float4 bv = *(const float4*)(by + col);
    float4 o;
    o.x = tanhf(a.x + b2.x + c2.x + d2.x + bv.x);
    o.y = tanhf(a.y + b2.y + c2.y + d2.y + bv.y);
    o.z = tanhf(a.z + b2.z + c2.z + d2.z + bv.z);
    o.w = tanhf(a.w + b2.w + c2.w + d2.w + bv.w);
    *(float4*)(yout + idx) = o;
}

// ---------------------------------------------------------------- launch
extern "C" void kernel_launch(void* const* d_in, const int* in_sizes, int n_in,
                              void* d_out, int out_size, void* d_ws, size_t ws_size,
                              hipStream_t stream) {
    const float* x   = (const float*)d_in[0];
    const float* c   = (const float*)d_in[1];
    const float* h   = (const float*)d_in[2];
    const float* Wxi = (const float*)d_in[3];
    const float* Whi = (const float*)d_in[4];
    const float* Bi  = (const float*)d_in[5];
    const float* Wxg = (const float*)d_in[6];
    const float* Whg = (const float*)d_in[7];
    const float* Bg  = (const float*)d_in[8];
    const float* Wxf = (const float*)d_in[9];
    const float* Whf = (const float*)d_in[10];
    const float* Bf  = (const float*)d_in[11];
    const float* Wxo = (const float*)d_in[12];
    const float* Who = (const float*)d_in[13];
    const float* Bo  = (const float*)d_in[14];
    const float* Why = (const float*)d_in[15];
    const float* By  = (const float*)d_in[16];

    const size_t BE = (size_t)B_SZ * E_SZ, BH = (size_t)B_SZ * H_SZ;
    const size_t HE = (size_t)H_SZ * E_SZ, HH = (size_t)H_SZ * H_SZ;
    const size_t EH = (size_t)E_SZ * H_SZ;

    unsigned short* ws   = (unsigned short*)d_ws;
    unsigned short* Xb   = ws;                 // BE
    unsigned short* Hb   = Xb + BE;            // BH
    unsigned short* Wxb  = Hb + BH;            // 4*HE
    unsigned short* Whb  = Wxb + 4 * HE;       // 4*HH
    unsigned short* Whyb = Whb + 4 * HH;       // EH
    unsigned short* Z    = Whyb + EH;          // 4*BH bf16; later fp32 y-partials
    unsigned short* HnB  = Z + 4 * BH;         // BH

    CastArgs ca;
    ca.src[0]  = x;   ca.dst[0]  = Xb;           ca.n[0]  = (int)BE;
    ca.src[1]  = h;   ca.dst[1]  = Hb;           ca.n[1]  = (int)BH;
    ca.src[2]  = Wxi; ca.dst[2]  = Wxb;          ca.n[2]  = (int)HE;
    ca.src[3]  = Wxg; ca.dst[3]  = Wxb + HE;     ca.n[3]  = (int)HE;
    ca.src[4]  = Wxf; ca.dst[4]  = Wxb + 2 * HE; ca.n[4]  = (int)HE;
    ca.src[5]  = Wxo; ca.dst[5]  = Wxb + 3 * HE; ca.n[5]  = (int)HE;
    ca.src[6]  = Whi; ca.dst[6]  = Whb;          ca.n[6]  = (int)HH;
    ca.src[7]  = Whg; ca.dst[7]  = Whb + HH;     ca.n[7]  = (int)HH;
    ca.src[8]  = Whf; ca.dst[8]  = Whb + 2 * HH; ca.n[8]  = (int)HH;
    ca.src[9]  = Who; ca.dst[9]  = Whb + 3 * HH; ca.n[9]  = (int)HH;
    ca.src[10] = Why; ca.dst[10] = Whyb;         ca.n[10] = (int)EH;

    hipLaunchKernelGGL(cast_kernel, dim3(1024, 11), dim3(256), 0, stream, ca);
    hipLaunchKernelGGL(gates8_kernel, dim3(256), dim3(512), 0, stream,
                       Xb, Hb, Wxb, Whb, Bi, Bg, Bf, Bo, Z);

    float* y_out = (float*)d_out;
    float* c_out = y_out + BE;
    float* h_out = c_out + BH;
    hipLaunchKernelGGL(cell_kernel, dim3((unsigned)(BH / 1024)), dim3(256), 0, stream,
                       Z, c, c_out, h_out, HnB);

    float* ypart = (float*)Z;   // Z dead after cell_kernel
    hipLaunchKernelGGL(y_split_kernel, dim3(256), dim3(256), 0, stream,
                       HnB, Whyb, ypart);
    hipLaunchKernelGGL(y_reduce_kernel, dim3((unsigned)(BE / 1024)), dim3(256), 0, stream,
                       ypart, By, y_out);
}

// Round 4
// 282.050 us; speedup vs baseline: 1.1529x; 1.1529x over previous
//
#include <hip/hip_runtime.h>

#define B_SZ 1024
#define H_SZ 2048
#define E_SZ 1024

typedef float  f32x4 __attribute__((ext_vector_type(4)));
typedef short  s16x8 __attribute__((ext_vector_type(8)));

__device__ __forceinline__ unsigned short f2bf(float f) {
    unsigned u = __float_as_uint(f);
    u = u + 0x7fffu + ((u >> 16) & 1u);   // RNE
    return (unsigned short)(u >> 16);
}
__device__ __forceinline__ float bf2f(unsigned short s) {
    return __uint_as_float(((unsigned)s) << 16);
}
__device__ __forceinline__ float sigm(float v) {
    return 1.0f / (1.0f + __expf(-v));
}
// packed f32x2 -> bf16x2, RNE (no builtin on gfx950; T12 recipe)
__device__ __forceinline__ unsigned cvtpk(float lo, float hi) {
    unsigned r;
    asm("v_cvt_pk_bf16_f32 %0, %1, %2" : "=v"(r) : "v"(lo), "v"(hi));
    return r;
}

__device__ __forceinline__ void gll(const unsigned short* g, unsigned short* l) {
    __builtin_amdgcn_global_load_lds(
        (const __attribute__((address_space(1))) unsigned int*)g,
        (__attribute__((address_space(3))) unsigned int*)l, 16, 0, 0);
}

// ---------------------------------------------------------------- cast pass
// Only x and h now (12 MB) — weights are read f32 directly by the GEMMs.
struct CastArgs {
    const float*    src[2];
    unsigned short* dst[2];
    int             n[2];
};

__global__ __launch_bounds__(256) void cast_kernel(CastArgs a) {
    const int arr = blockIdx.y;
    const int n = a.n[arr];
    const float* __restrict__ s = a.src[arr];
    unsigned short* __restrict__ d = a.dst[arr];
    const int stride = gridDim.x * 256 * 4;
    for (int i = (blockIdx.x * 256 + threadIdx.x) * 4; i < n; i += stride) {
        float4 v = *(const float4*)(s + i);
        ushort4 o;
        o.x = f2bf(v.x); o.y = f2bf(v.y); o.z = f2bf(v.z); o.w = f2bf(v.w);
        *(ushort4*)(d + i) = o;
    }
}

// ------------------------- bf16 GEMM core, BK=64 + swizzle, f32 B-operand
// R0-proven structure (128x128 tile, 2 blocks/CU implicit overlap).
// A (activations, bf16, L2/L3-resident) staged via global_load_lds.
// W (weights) read f32 DIRECTLY from the input tensors and converted during
// staging: 2x float4 load -> 4x v_cvt_pk_bf16_f32 -> ds_write_b128, into the
// SAME swizzled LDS layout the gll path used (fragment reads unchanged).
// This kills the 225 MB weight-cast round-trip through HBM.
__device__ __forceinline__ void gemm_accum64_bf32(
    const unsigned short* __restrict__ A,
    const float* __restrict__ W,
    int ld, int kLen, int m0, int n0,
    unsigned short* lA, unsigned short* lB,
    f32x4 acc[4][4], int t)
{
    const int lane = t & 63;
    const int w    = t >> 6;
    const int wr   = (w >> 1) << 6;   // wave row offset in 128-tile
    const int wc   = (w & 1) << 6;    // wave col offset
    const int lr   = lane & 15;
    const int q4   = lane >> 4;       // 0..3

    // staging: chunk c = t + 256p  ->  row = c>>3 (=srow+32p), colblk = t&7
    // (row&7) == (srow&7) for all p since 32p % 8 == 0, so one scol works.
    const int srow = t >> 3;                              // 0..31
    const int scol = ((t & 7) ^ (srow & 7)) << 3;         // swizzled col
    const unsigned short* gA = A + (size_t)(m0 + srow) * ld + scol;
    const float*          gB = W + (size_t)(n0 + srow) * ld + scol;
    const size_t st32 = (size_t)32 * ld;

    // fragment read offsets (elements) for k-sub-step 0/1
    const int cb0 = ((q4    ) ^ (lr & 7)) << 3;
    const int cb1 = ((4 + q4) ^ (lr & 7)) << 3;

    for (int k0 = 0; k0 < kLen; k0 += 64) {
        // B: issue all 8 f32 global loads early
        float4 f[4][2];
#pragma unroll
        for (int p = 0; p < 4; ++p) {
            const float* src = gB + k0 + p * st32;
            f[p][0] = *(const float4*)(src);
            f[p][1] = *(const float4*)(src + 4);
        }
        // A: async global->LDS
#pragma unroll
        for (int p = 0; p < 4; ++p)
            gll(gA + k0 + p * st32, lA + (t + 256 * p) * 8);
        // B: convert + LDS write (same linear dest the gll path used)
#pragma unroll
        for (int p = 0; p < 4; ++p) {
            uint4 pk;
            pk.x = cvtpk(f[p][0].x, f[p][0].y);
            pk.y = cvtpk(f[p][0].z, f[p][0].w);
            pk.z = cvtpk(f[p][1].x, f[p][1].y);
            pk.w = cvtpk(f[p][1].z, f[p][1].w);
            *(uint4*)(lB + (t + 256 * p) * 8) = pk;
        }
        __syncthreads();

#pragma unroll
        for (int ks = 0; ks < 2; ++ks) {
            const int cb = ks ? cb1 : cb0;
            s16x8 af[4], bfr[4];
#pragma unroll
            for (int i = 0; i < 4; ++i)
                af[i] = *(const s16x8*)(lA + (wr + i * 16 + lr) * 64 + cb);
#pragma unroll
            for (int j = 0; j < 4; ++j)
                bfr[j] = *(const s16x8*)(lB + (wc + j * 16 + lr) * 64 + cb);
#pragma unroll
            for (int i = 0; i < 4; ++i)
#pragma unroll
                for (int j = 0; j < 4; ++j)
                    acc[i][j] = __builtin_amdgcn_mfma_f32_16x16x32_bf16(
                        af[i], bfr[j], acc[i][j], 0, 0, 0);
        }
        __syncthreads();
    }
}

// -------------------------------------------------------------- gate GEMMs
struct GatesArgs {
    const unsigned short *Xb, *Hb;
    const float *Wx[4], *Wh[4], *bias[4];
    unsigned short *Z;
};

__global__ __launch_bounds__(256) void gates_kernel(GatesArgs a) {
    __shared__ unsigned short lA[128 * 64];
    __shared__ unsigned short lB[128 * 64];
    const int t   = threadIdx.x;
    const int b   = blockIdx.x;
    const int xcd = b & 7;
    const int i_  = b >> 3;                 // 0..63 within XCD
    const int nt  = xcd * 8 + (i_ >> 3);    // 0..63 weight tile (q,n0)
    const int m0  = (i_ & 7) * 128;
    const int q   = nt >> 4;
    const int n0  = (nt & 15) * 128;

    f32x4 acc[4][4] = {};
    gemm_accum64_bf32(a.Xb, a.Wx[q], E_SZ, E_SZ, m0, n0, lA, lB, acc, t);
    gemm_accum64_bf32(a.Hb, a.Wh[q], H_SZ, H_SZ, m0, n0, lA, lB, acc, t);

    const float* bias = a.bias[q];
    const int lane = t & 63, w = t >> 6;
    const int wr = (w >> 1) << 6, wc = (w & 1) << 6;
    const int lr = lane & 15, rq = (lane >> 4) << 2;
    unsigned short* Zq = a.Z + (size_t)q * B_SZ * H_SZ;
#pragma unroll
    for (int i = 0; i < 4; ++i) {
#pragma unroll
        for (int j = 0; j < 4; ++j) {
            const int n = n0 + wc + j * 16 + lr;
            const float bv = bias[n];
#pragma unroll
            for (int r = 0; r < 4; ++r) {
                const int m = m0 + wr + i * 16 + rq + r;
                const float v = acc[i][j][r] + bv;
                const float act = (q == 1) ? tanhf(v) : sigm(v);
                Zq[(size_t)m * H_SZ + n] = f2bf(act);
            }
        }
    }
}

// ------------------------------------------------------------ cell update
__global__ __launch_bounds__(256) void cell_kernel(
    const unsigned short* __restrict__ Z, const float* __restrict__ c,
    float* __restrict__ c_out, float* __restrict__ h_out,
    unsigned short* __restrict__ HnB)
{
    const size_t BH = (size_t)B_SZ * H_SZ;
    const int idx = (blockIdx.x * 256 + threadIdx.x) * 4;
    ushort4 iu = *(const ushort4*)(Z + idx);
    ushort4 gu = *(const ushort4*)(Z + BH + idx);
    ushort4 fu = *(const ushort4*)(Z + 2 * BH + idx);
    ushort4 ou = *(const ushort4*)(Z + 3 * BH + idx);
    float4 cv = *(const float4*)(c + idx);

    float cn[4], hn[4];
    cn[0] = bf2f(fu.x) * cv.x + bf2f(iu.x) * bf2f(gu.x);
    cn[1] = bf2f(fu.y) * cv.y + bf2f(iu.y) * bf2f(gu.y);
    cn[2] = bf2f(fu.z) * cv.z + bf2f(iu.z) * bf2f(gu.z);
    cn[3] = bf2f(fu.w) * cv.w + bf2f(iu.w) * bf2f(gu.w);
    hn[0] = bf2f(ou.x) * cn[0];
    hn[1] = bf2f(ou.y) * cn[1];
    hn[2] = bf2f(ou.z) * cn[2];
    hn[3] = bf2f(ou.w) * cn[3];

    *(float4*)(c_out + idx) = make_float4(cn[0], cn[1], cn[2], cn[3]);
    *(float4*)(h_out + idx) = make_float4(hn[0], hn[1], hn[2], hn[3]);
    ushort4 hb;
    hb.x = f2bf(hn[0]); hb.y = f2bf(hn[1]); hb.z = f2bf(hn[2]); hb.w = f2bf(hn[3]);
    *(ushort4*)(HnB + idx) = hb;
}

// ---------------------------------------------------- y GEMM, split-K by 4
__global__ __launch_bounds__(256) void y_split_kernel(
    const unsigned short* __restrict__ Hn,
    const float* __restrict__ Wy,
    float* __restrict__ part)
{
    __shared__ unsigned short lA[128 * 64];
    __shared__ unsigned short lB[128 * 64];
    const int t   = threadIdx.x;
    const int b   = blockIdx.x;
    const int xcd = b & 7;
    const int i_  = b >> 3;                 // 0..31 within XCD
    const int ns  = xcd * 4 + (i_ >> 3);    // 0..31: (n-tile, split)
    const int m0  = (i_ & 7) * 128;
    const int n0  = (ns >> 2) * 128;
    const int s   = ns & 3;

    f32x4 acc[4][4] = {};
    gemm_accum64_bf32(Hn + s * 512, Wy + s * 512, H_SZ, 512, m0, n0, lA, lB, acc, t);

    const int lane = t & 63, w = t >> 6;
    const int wr = (w >> 1) << 6, wc = (w & 1) << 6;
    const int lr = lane & 15, rq = (lane >> 4) << 2;
    float* P = part + (size_t)s * B_SZ * E_SZ;
#pragma unroll
    for (int i = 0; i < 4; ++i) {
#pragma unroll
        for (int j = 0; j < 4; ++j) {
            const int n = n0 + wc + j * 16 + lr;
#pragma unroll
            for (int r = 0; r < 4; ++r) {
                const int m = m0 + wr + i * 16 + rq + r;
                P[(size_t)m * E_SZ + n] = acc[i][j][r];
            }
        }
    }
}

__global__ __launch_bounds__(256) void y_reduce_kernel(
    const float* __restrict__ part, const float* __restrict__ by,
    float* __restrict__ yout)
{
    const size_t BE = (size_t)B_SZ * E_SZ;
    const int idx = (blockIdx.x * 256 + threadIdx.x) * 4;
    float4 a = *(const float4*)(part + idx);
    float4 b2 = *(const float4*)(part + BE + idx);
    float4 c2 = *(const float4*)(part + 2 * BE + idx);
    float4 d2 = *(const float4*)(part + 3 * BE + idx);
    const int col = idx & (E_SZ - 1);
    float4 bv = *(const float4*)(by + col);
    float4 o;
    o.x = tanhf(a.x + b2.x + c2.x + d2.x + bv.x);
    o.y = tanhf(a.y + b2.y + c2.y + d2.y + bv.y);
    o.z = tanhf(a.z + b2.z + c2.z + d2.z + bv.z);
    o.w = tanhf(a.w + b2.w + c2.w + d2.w + bv.w);
    *(float4*)(yout + idx) = o;
}

// ---------------------------------------------------------------- launch
extern "C" void kernel_launch(void* const* d_in, const int* in_sizes, int n_in,
                              void* d_out, int out_size, void* d_ws, size_t ws_size,
                              hipStream_t stream) {
    const float* x   = (const float*)d_in[0];
    const float* c   = (const float*)d_in[1];
    const float* h   = (const float*)d_in[2];
    const float* Wxi = (const float*)d_in[3];
    const float* Whi = (const float*)d_in[4];
    const float* Bi  = (const float*)d_in[5];
    const float* Wxg = (const float*)d_in[6];
    const float* Whg = (const float*)d_in[7];
    const float* Bg  = (const float*)d_in[8];
    const float* Wxf = (const float*)d_in[9];
    const float* Whf = (const float*)d_in[10];
    const float* Bf  = (const float*)d_in[11];
    const float* Wxo = (const float*)d_in[12];
    const float* Who = (const float*)d_in[13];
    const float* Bo  = (const float*)d_in[14];
    const float* Why = (const float*)d_in[15];
    const float* By  = (const float*)d_in[16];

    const size_t BE = (size_t)B_SZ * E_SZ, BH = (size_t)B_SZ * H_SZ;

    unsigned short* ws  = (unsigned short*)d_ws;
    unsigned short* Xb  = ws;                 // BE bf16
    unsigned short* Hb  = Xb + BE;            // BH bf16
    unsigned short* Z   = Hb + BH;            // 4*BH bf16; later fp32 y-partials
    unsigned short* HnB = Z + 4 * BH;         // BH bf16

    CastArgs ca;
    ca.src[0] = x; ca.dst[0] = Xb; ca.n[0] = (int)BE;
    ca.src[1] = h; ca.dst[1] = Hb; ca.n[1] = (int)BH;
    hipLaunchKernelGGL(cast_kernel, dim3(512, 2), dim3(256), 0, stream, ca);

    GatesArgs ga;
    ga.Xb = Xb; ga.Hb = Hb;
    ga.Wx[0] = Wxi; ga.Wx[1] = Wxg; ga.Wx[2] = Wxf; ga.Wx[3] = Wxo;
    ga.Wh[0] = Whi; ga.Wh[1] = Whg; ga.Wh[2] = Whf; ga.Wh[3] = Who;
    ga.bias[0] = Bi; ga.bias[1] = Bg; ga.bias[2] = Bf; ga.bias[3] = Bo;
    ga.Z = Z;
    hipLaunchKernelGGL(gates_kernel, dim3(512), dim3(256), 0, stream, ga);

    float* y_out = (float*)d_out;
    float* c_out = y_out + BE;
    float* h_out = c_out + BH;
    hipLaunchKernelGGL(cell_kernel, dim3((unsigned)(BH / 1024)), dim3(256), 0, stream,
                       Z, c, c_out, h_out, HnB);

    float* ypart = (float*)Z;   // Z dead after cell_kernel
    hipLaunchKernelGGL(y_split_kernel, dim3(256), dim3(256), 0, stream,
                       HnB, Why, ypart);
    hipLaunchKernelGGL(y_reduce_kernel, dim3((unsigned)(BE / 1024)), dim3(256), 0, stream,
                       ypart, By, y_out);
}

// Round 6
// 274.492 us; speedup vs baseline: 1.1847x; 1.0275x over previous
//
#include <hip/hip_runtime.h>

#define B_SZ 1024
#define H_SZ 2048
#define E_SZ 1024

typedef float  f32x4 __attribute__((ext_vector_type(4)));
typedef short  s16x8 __attribute__((ext_vector_type(8)));

__device__ __forceinline__ unsigned short f2bf(float f) {
    unsigned u = __float_as_uint(f);
    u = u + 0x7fffu + ((u >> 16) & 1u);   // RNE
    return (unsigned short)(u >> 16);
}
__device__ __forceinline__ float bf2f(unsigned short s) {
    return __uint_as_float(((unsigned)s) << 16);
}
__device__ __forceinline__ float sigm(float v) {
    return 1.0f / (1.0f + __expf(-v));
}
// packed f32x2 -> bf16x2, RNE (no builtin on gfx950)
__device__ __forceinline__ unsigned cvtpk(float lo, float hi) {
    unsigned r;
    asm("v_cvt_pk_bf16_f32 %0, %1, %2" : "=v"(r) : "v"(lo), "v"(hi));
    return r;
}

__device__ __forceinline__ void gll(const unsigned short* g, unsigned short* l) {
    __builtin_amdgcn_global_load_lds(
        (const __attribute__((address_space(1))) unsigned int*)g,
        (__attribute__((address_space(3))) unsigned int*)l, 16, 0, 0);
}

// ---------------------------------------------------------------- cast pass
// Only x and h (12 MB) — weights are read f32 directly by the GEMMs.
struct CastArgs {
    const float*    src[2];
    unsigned short* dst[2];
    int             n[2];
};

__global__ __launch_bounds__(256) void cast_kernel(CastArgs a) {
    const int arr = blockIdx.y;
    const int n = a.n[arr];
    const float* __restrict__ s = a.src[arr];
    unsigned short* __restrict__ d = a.dst[arr];
    const int stride = gridDim.x * 256 * 4;
    for (int i = (blockIdx.x * 256 + threadIdx.x) * 4; i < n; i += stride) {
        float4 v = *(const float4*)(s + i);
        ushort4 o;
        o.x = f2bf(v.x); o.y = f2bf(v.y); o.z = f2bf(v.z); o.w = f2bf(v.w);
        *(ushort4*)(d + i) = o;
    }
}

// ---------------- bf16 GEMM core, BK=128, f32 B-operand, T14 staging ------
// 128x128 tile, 64KB LDS -> 2 blocks/CU (m114 implicit overlap preserved).
// BK=128 halves the number of barrier-drain latency exposures (48 -> 24 for
// gates). B (f32 weights, HBM-streamed) is reg-staged with issue-early/
// write-late: loads for tile k+128 are ISSUED right after sync#1 and
// consumed (cvt_pk + ds_write_b128) at the top of the next iteration, so the
// whole 64-MFMA phase covers their ~900cy HBM latency. A (bf16 activations,
// L2/L3-resident) stays on async global_load_lds.
// LDS layout (both tiles): row = chunk>>4, pos16 = chunk&15; slot (row,pos)
// holds global 8-elem col-block (pos ^ (row&15)) — pre-swizzled source,
// linear dest (rule #21). ds_read_b128 octets then span all 8 bank groups.
__device__ __forceinline__ void gemm_bk128(
    const unsigned short* __restrict__ A,
    const float* __restrict__ W,
    int ld, int kLen, int m0, int n0,
    unsigned short* lA, unsigned short* lB,
    f32x4 acc[4][4], int t)
{
    const int lane = t & 63;
    const int w    = t >> 6;
    const int wr   = (w >> 1) << 6;   // wave row offset in 128-tile
    const int wc   = (w & 1) << 6;    // wave col offset
    const int lr   = lane & 15;
    const int q4   = lane >> 4;       // 0..3

    // staging: chunk c = t + 256p -> row = (t>>4)+16p, pos16 = t&15.
    // (row&15) == (t>>4) for all p, so one pre-swizzled source col works.
    const int srow = t >> 4;                      // 0..15
    const int sblk = ((t & 15) ^ srow) << 3;      // swizzled col (elems)
    const unsigned short* gA = A + (size_t)(m0 + srow) * ld + sblk;
    const float*          gW = W + (size_t)(n0 + srow) * ld + sblk;
    const size_t st16 = (size_t)16 * ld;

    // B prefetch registers: 8 chunks x 8 f32
    f32x4 f0[8], f1[8];
#pragma unroll
    for (int p = 0; p < 8; ++p) {                 // prologue: issue B(0)
        const float* s = gW + p * st16;
        f0[p] = *(const f32x4*)(s);
        f1[p] = *(const f32x4*)(s + 4);
    }

    for (int k0 = 0; k0 < kLen; k0 += 128) {
        // write-late: convert B(k0) regs (issued one phase ago) -> LDS
#pragma unroll
        for (int p = 0; p < 8; ++p) {
            uint4 pk;
            pk.x = cvtpk(f0[p].x, f0[p].y);
            pk.y = cvtpk(f0[p].z, f0[p].w);
            pk.z = cvtpk(f1[p].x, f1[p].y);
            pk.w = cvtpk(f1[p].z, f1[p].w);
            *(uint4*)(lB + (t + 256 * p) * 8) = pk;
        }
        // A: async global->LDS
#pragma unroll
        for (int p = 0; p < 8; ++p)
            gll(gA + k0 + p * st16, lA + (t + 256 * p) * 8);
        __syncthreads();

        // issue-early: next B tile (covered by the MFMA phase below)
        if (k0 + 128 < kLen) {
#pragma unroll
            for (int p = 0; p < 8; ++p) {
                const float* s = gW + (k0 + 128) + p * st16;
                f0[p] = *(const f32x4*)(s);
                f1[p] = *(const f32x4*)(s + 4);
            }
        }

#pragma unroll
        for (int ks = 0; ks < 4; ++ks) {
            s16x8 af[4], bfr[4];
#pragma unroll
            for (int i = 0; i < 4; ++i) {
                const int ra = wr + i * 16 + lr;
                af[i] = *(const s16x8*)(lA + ra * 128 +
                         ((((ks << 2) + q4) ^ (ra & 15)) << 3));
            }
#pragma unroll
            for (int j = 0; j < 4; ++j) {
                const int rb = wc + j * 16 + lr;
                bfr[j] = *(const s16x8*)(lB + rb * 128 +
                          ((((ks << 2) + q4) ^ (rb & 15)) << 3));
            }
#pragma unroll
            for (int i = 0; i < 4; ++i)
#pragma unroll
                for (int j = 0; j < 4; ++j)
                    acc[i][j] = __builtin_amdgcn_mfma_f32_16x16x32_bf16(
                        af[i], bfr[j], acc[i][j], 0, 0, 0);
        }
        __syncthreads();
    }
}

// -------------------------------------------------------------- gate GEMMs
struct GatesArgs {
    const unsigned short *Xb, *Hb;
    const float *Wx[4], *Wh[4], *bias[4];
    unsigned short *Z;
};

__global__ __launch_bounds__(256, 2) void gates_kernel(GatesArgs a) {
    __shared__ unsigned short lA[128 * 128];
    __shared__ unsigned short lB[128 * 128];
    const int t   = threadIdx.x;
    const int b   = blockIdx.x;
    const int xcd = b & 7;
    const int i_  = b >> 3;                 // 0..63 within XCD
    const int nt  = xcd * 8 + (i_ >> 3);    // 0..63 weight tile (q,n0)
    const int m0  = (i_ & 7) * 128;
    const int q   = nt >> 4;
    const int n0  = (nt & 15) * 128;

    f32x4 acc[4][4] = {};
    gemm_bk128(a.Xb, a.Wx[q], E_SZ, E_SZ, m0, n0, lA, lB, acc, t);
    gemm_bk128(a.Hb, a.Wh[q], H_SZ, H_SZ, m0, n0, lA, lB, acc, t);

    const float* bias = a.bias[q];
    const int lane = t & 63, w = t >> 6;
    const int wr = (w >> 1) << 6, wc = (w & 1) << 6;
    const int lr = lane & 15, rq = (lane >> 4) << 2;
    unsigned short* Zq = a.Z + (size_t)q * B_SZ * H_SZ;
#pragma unroll
    for (int i = 0; i < 4; ++i) {
#pragma unroll
        for (int j = 0; j < 4; ++j) {
            const int n = n0 + wc + j * 16 + lr;
            const float bv = bias[n];
#pragma unroll
            for (int r = 0; r < 4; ++r) {
                const int m = m0 + wr + i * 16 + rq + r;
                const float v = acc[i][j][r] + bv;
                const float act = (q == 1) ? tanhf(v) : sigm(v);
                Zq[(size_t)m * H_SZ + n] = f2bf(act);
            }
        }
    }
}

// ------------------------------------------------------------ cell update
__global__ __launch_bounds__(256) void cell_kernel(
    const unsigned short* __restrict__ Z, const float* __restrict__ c,
    float* __restrict__ c_out, float* __restrict__ h_out,
    unsigned short* __restrict__ HnB)
{
    const size_t BH = (size_t)B_SZ * H_SZ;
    const int idx = (blockIdx.x * 256 + threadIdx.x) * 4;
    ushort4 iu = *(const ushort4*)(Z + idx);
    ushort4 gu = *(const ushort4*)(Z + BH + idx);
    ushort4 fu = *(const ushort4*)(Z + 2 * BH + idx);
    ushort4 ou = *(const ushort4*)(Z + 3 * BH + idx);
    float4 cv = *(const float4*)(c + idx);

    float cn[4], hn[4];
    cn[0] = bf2f(fu.x) * cv.x + bf2f(iu.x) * bf2f(gu.x);
    cn[1] = bf2f(fu.y) * cv.y + bf2f(iu.y) * bf2f(gu.y);
    cn[2] = bf2f(fu.z) * cv.z + bf2f(iu.z) * bf2f(gu.z);
    cn[3] = bf2f(fu.w) * cv.w + bf2f(iu.w) * bf2f(gu.w);
    hn[0] = bf2f(ou.x) * cn[0];
    hn[1] = bf2f(ou.y) * cn[1];
    hn[2] = bf2f(ou.z) * cn[2];
    hn[3] = bf2f(ou.w) * cn[3];

    *(float4*)(c_out + idx) = make_float4(cn[0], cn[1], cn[2], cn[3]);
    *(float4*)(h_out + idx) = make_float4(hn[0], hn[1], hn[2], hn[3]);
    ushort4 hb;
    hb.x = f2bf(hn[0]); hb.y = f2bf(hn[1]); hb.z = f2bf(hn[2]); hb.w = f2bf(hn[3]);
    *(ushort4*)(HnB + idx) = hb;
}

// ---------------------------------------------------- y GEMM, split-K by 4
__global__ __launch_bounds__(256, 2) void y_split_kernel(
    const unsigned short* __restrict__ Hn,
    const float* __restrict__ Wy,
    float* __restrict__ part)
{
    __shared__ unsigned short lA[128 * 128];
    __shared__ unsigned short lB[128 * 128];
    const int t   = threadIdx.x;
    const int b   = blockIdx.x;
    const int xcd = b & 7;
    const int i_  = b >> 3;                 // 0..31 within XCD
    const int ns  = xcd * 4 + (i_ >> 3);    // 0..31: (n-tile, split)
    const int m0  = (i_ & 7) * 128;
    const int n0  = (ns >> 2) * 128;
    const int s   = ns & 3;

    f32x4 acc[4][4] = {};
    gemm_bk128(Hn + s * 512, Wy + s * 512, H_SZ, 512, m0, n0, lA, lB, acc, t);

    const int lane = t & 63, w = t >> 6;
    const int wr = (w >> 1) << 6, wc = (w & 1) << 6;
    const int lr = lane & 15, rq = (lane >> 4) << 2;
    float* P = part + (size_t)s * B_SZ * E_SZ;
#pragma unroll
    for (int i = 0; i < 4; ++i) {
#pragma unroll
        for (int j = 0; j < 4; ++j) {
            const int n = n0 + wc + j * 16 + lr;
#pragma unroll
            for (int r = 0; r < 4; ++r) {
                const int m = m0 + wr + i * 16 + rq + r;
                P[(size_t)m * E_SZ + n] = acc[i][j][r];
            }
        }
    }
}

__global__ __launch_bounds__(256) void y_reduce_kernel(
    const float* __restrict__ part, const float* __restrict__ by,
    float* __restrict__ yout)
{
    const size_t BE = (size_t)B_SZ * E_SZ;
    const int idx = (blockIdx.x * 256 + threadIdx.x) * 4;
    float4 a = *(const float4*)(part + idx);
    float4 b2 = *(const float4*)(part + BE + idx);
    float4 c2 = *(const float4*)(part + 2 * BE + idx);
    float4 d2 = *(const float4*)(part + 3 * BE + idx);
    const int col = idx & (E_SZ - 1);
    float4 bv = *(const float4*)(by + col);
    float4 o;
    o.x = tanhf(a.x + b2.x + c2.x + d2.x + bv.x);
    o.y = tanhf(a.y + b2.y + c2.y + d2.y + bv.y);
    o.z = tanhf(a.z + b2.z + c2.z + d2.z + bv.z);
    o.w = tanhf(a.w + b2.w + c2.w + d2.w + bv.w);
    *(float4*)(yout + idx) = o;
}

// ---------------------------------------------------------------- launch
extern "C" void kernel_launch(void* const* d_in, const int* in_sizes, int n_in,
                              void* d_out, int out_size, void* d_ws, size_t ws_size,
                              hipStream_t stream) {
    const float* x   = (const float*)d_in[0];
    const float* c   = (const float*)d_in[1];
    const float* h   = (const float*)d_in[2];
    const float* Wxi = (const float*)d_in[3];
    const float* Whi = (const float*)d_in[4];
    const float* Bi  = (const float*)d_in[5];
    const float* Wxg = (const float*)d_in[6];
    const float* Whg = (const float*)d_in[7];
    const float* Bg  = (const float*)d_in[8];
    const float* Wxf = (const float*)d_in[9];
    const float* Whf = (const float*)d_in[10];
    const float* Bf  = (const float*)d_in[11];
    const float* Wxo = (const float*)d_in[12];
    const float* Who = (const float*)d_in[13];
    const float* Bo  = (const float*)d_in[14];
    const float* Why = (const float*)d_in[15];
    const float* By  = (const float*)d_in[16];

    const size_t BE = (size_t)B_SZ * E_SZ, BH = (size_t)B_SZ * H_SZ;

    unsigned short* ws  = (unsigned short*)d_ws;
    unsigned short* Xb  = ws;                 // BE bf16
    unsigned short* Hb  = Xb + BE;            // BH bf16
    unsigned short* Z   = Hb + BH;            // 4*BH bf16; later fp32 y-partials
    unsigned short* HnB = Z + 4 * BH;         // BH bf16

    CastArgs ca;
    ca.src[0] = x; ca.dst[0] = Xb; ca.n[0] = (int)BE;
    ca.src[1] = h; ca.dst[1] = Hb; ca.n[1] = (int)BH;
    hipLaunchKernelGGL(cast_kernel, dim3(512, 2), dim3(256), 0, stream, ca);

    GatesArgs ga;
    ga.Xb = Xb; ga.Hb = Hb;
    ga.Wx[0] = Wxi; ga.Wx[1] = Wxg; ga.Wx[2] = Wxf; ga.Wx[3] = Wxo;
    ga.Wh[0] = Whi; ga.Wh[1] = Whg; ga.Wh[2] = Whf; ga.Wh[3] = Who;
    ga.bias[0] = Bi; ga.bias[1] = Bg; ga.bias[2] = Bf; ga.bias[3] = Bo;
    ga.Z = Z;
    hipLaunchKernelGGL(gates_kernel, dim3(512), dim3(256), 0, stream, ga);

    float* y_out = (float*)d_out;
    float* c_out = y_out + BE;
    float* h_out = c_out + BH;
    hipLaunchKernelGGL(cell_kernel, dim3((unsigned)(BH / 1024)), dim3(256), 0, stream,
                       Z, c, c_out, h_out, HnB);

    float* ypart = (float*)Z;   // Z dead after cell_kernel
    hipLaunchKernelGGL(y_split_kernel, dim3(256), dim3(256), 0, stream,
                       HnB, Why, ypart);
    hipLaunchKernelGGL(y_reduce_kernel, dim3((unsigned)(BE / 1024)), dim3(256), 0, stream,
                       ypart, By, y_out);
}

// Round 8
// 262.437 us; speedup vs baseline: 1.2391x; 1.0459x over previous
//
#include <hip/hip_runtime.h>

#define B_SZ 1024
#define H_SZ 2048
#define E_SZ 1024

typedef float  f32x4 __attribute__((ext_vector_type(4)));
typedef short  s16x8 __attribute__((ext_vector_type(8)));

__device__ __forceinline__ unsigned short f2bf(float f) {
    unsigned u = __float_as_uint(f);
    u = u + 0x7fffu + ((u >> 16) & 1u);   // RNE
    return (unsigned short)(u >> 16);
}
__device__ __forceinline__ float bf2f(unsigned short s) {
    return __uint_as_float(((unsigned)s) << 16);
}
__device__ __forceinline__ float sigm(float v) {
    return 1.0f / (1.0f + __expf(-v));
}
// packed f32x2 -> bf16x2, RNE (no builtin on gfx950)
__device__ __forceinline__ unsigned cvtpk(float lo, float hi) {
    unsigned r;
    asm("v_cvt_pk_bf16_f32 %0, %1, %2" : "=v"(r) : "v"(lo), "v"(hi));
    return r;
}

__device__ __forceinline__ void gll(const unsigned short* g, unsigned short* l) {
    __builtin_amdgcn_global_load_lds(
        (const __attribute__((address_space(1))) unsigned int*)g,
        (__attribute__((address_space(3))) unsigned int*)l, 16, 0, 0);
}

// ---------------------------------------------------------------- cast pass
// x, h, and the 8 gate weights (162 MB). Why stays f32 (y_split f32 path).
struct CastArgs {
    const float*    src[10];
    unsigned short* dst[10];
    int             n[10];
};

__global__ __launch_bounds__(256) void cast_kernel(CastArgs a) {
    const int arr = blockIdx.y;
    const int n = a.n[arr];
    const float* __restrict__ s = a.src[arr];
    unsigned short* __restrict__ d = a.dst[arr];
    const int stride = gridDim.x * 256 * 4;
    for (int i = (blockIdx.x * 256 + threadIdx.x) * 4; i < n; i += stride) {
        float4 v = *(const float4*)(s + i);
        ushort4 o;
        o.x = f2bf(v.x); o.y = f2bf(v.y); o.z = f2bf(v.z); o.w = f2bf(v.w);
        *(ushort4*)(d + i) = o;
    }
}

// ------------- R0-proven bf16 GEMM core, 4-gate B packing, BK=64 ----------
// Identical LDS layout / swizzle / fragment reads / MFMA loop to the 68.6us
// R0 gates core. B-tile's 128 LDS rows = [gate q = row>>5][local n 0..31]:
// staging chunk p (rows 32p..32p+31) maps exactly to gate p, so the only
// change vs R0 is four per-gate global source bases.
__device__ __forceinline__ void gemm_gates4(
    const unsigned short* __restrict__ A,
    const unsigned short* __restrict__ W0,
    const unsigned short* __restrict__ W1,
    const unsigned short* __restrict__ W2,
    const unsigned short* __restrict__ W3,
    int ld, int kLen, int m0, int n0h,
    unsigned short* lA, unsigned short* lB,
    f32x4 acc[4][4], int t)
{
    const int lane = t & 63;
    const int w    = t >> 6;
    const int wr   = (w >> 1) << 6;   // wave row offset
    const int wc   = (w & 1) << 6;    // wave col offset (block-N of 128)
    const int lr   = lane & 15;
    const int q4   = lane >> 4;       // 0..3

    const int srow = t >> 3;                              // 0..31
    const int scol = ((t & 7) ^ (srow & 7)) << 3;         // swizzled col
    const unsigned short* gA = A + (size_t)(m0 + srow) * ld + scol;
    const size_t st32 = (size_t)32 * ld;
    const size_t boff = (size_t)(n0h + srow) * ld + scol;
    const unsigned short* gB0 = W0 + boff;
    const unsigned short* gB1 = W1 + boff;
    const unsigned short* gB2 = W2 + boff;
    const unsigned short* gB3 = W3 + boff;

    const int cb0 = ((q4    ) ^ (lr & 7)) << 3;
    const int cb1 = ((4 + q4) ^ (lr & 7)) << 3;

    for (int k0 = 0; k0 < kLen; k0 += 64) {
#pragma unroll
        for (int p = 0; p < 4; ++p)
            gll(gA + k0 + p * st32, lA + (t + 256 * p) * 8);
        gll(gB0 + k0, lB + t * 8);
        gll(gB1 + k0, lB + (t + 256) * 8);
        gll(gB2 + k0, lB + (t + 512) * 8);
        gll(gB3 + k0, lB + (t + 768) * 8);
        __syncthreads();

#pragma unroll
        for (int ks = 0; ks < 2; ++ks) {
            const int cb = ks ? cb1 : cb0;
            s16x8 af[4], bfr[4];
#pragma unroll
            for (int i = 0; i < 4; ++i)
                af[i] = *(const s16x8*)(lA + (wr + i * 16 + lr) * 64 + cb);
#pragma unroll
            for (int j = 0; j < 4; ++j)
                bfr[j] = *(const s16x8*)(lB + (wc + j * 16 + lr) * 64 + cb);
#pragma unroll
            for (int i = 0; i < 4; ++i)
#pragma unroll
                for (int j = 0; j < 4; ++j)
                    acc[i][j] = __builtin_amdgcn_mfma_f32_16x16x32_bf16(
                        af[i], bfr[j], acc[i][j], 0, 0, 0);
        }
        __syncthreads();
    }
}

// --------------------------------------------- gates + cell, fused kernel
// Block = 128 batch rows x 32 H-cols x ALL 4 gates (block-N = 128).
// Grid 8 m x 64 n = 512 blocks, 32KB LDS -> 2 blocks/CU (m114 overlap).
// Epilogue: bias+activation -> 32KB LDS exchange -> cell update -> write
// c_out / h_out / HnB directly. Z buffer and cell kernel eliminated.
struct GatesCellArgs {
    const unsigned short *Xb, *Hb, *Wxb, *Whb;
    const float *bias[4];
    const float *cin;
    float *c_out, *h_out;
    unsigned short *HnB;
};

__global__ __launch_bounds__(256, 2) void gates_cell_kernel(GatesCellArgs a) {
    __shared__ unsigned short smem[16384];    // staging lA|lB; then exchange
    unsigned short* lA = smem;
    unsigned short* lB = smem + 8192;

    const int t   = threadIdx.x;
    const int b   = blockIdx.x;
    const int xcd = b & 7;
    const int i_  = b >> 3;                 // 0..63 within XCD
    const int nt  = xcd * 8 + (i_ >> 3);    // 0..63 n-tile (32 H-cols)
    const int m0  = (i_ & 7) * 128;
    const int n0h = nt * 32;

    const size_t HE = (size_t)H_SZ * E_SZ, HH = (size_t)H_SZ * H_SZ;

    f32x4 acc[4][4] = {};
    gemm_gates4(a.Xb, a.Wxb, a.Wxb + HE, a.Wxb + 2 * HE, a.Wxb + 3 * HE,
                E_SZ, E_SZ, m0, n0h, lA, lB, acc, t);
    gemm_gates4(a.Hb, a.Whb, a.Whb + HH, a.Whb + 2 * HH, a.Whb + 3 * HH,
                H_SZ, H_SZ, m0, n0h, lA, lB, acc, t);

    // ---- epilogue 1: bias + activation -> LDS exchange [row128][col128]
    const int lane = t & 63, w = t >> 6;
    const int wr = (w >> 1) << 6, wc = (w & 1) << 6;
    const int lr = lane & 15, rq = (lane >> 4) << 2;
#pragma unroll
    for (int j = 0; j < 4; ++j) {
        const int col = wc + j * 16 + lr;       // 0..127 block-N
        const int q   = col >> 5;               // gate (wave-uniform)
        const float bv = a.bias[q][n0h + (col & 31)];
#pragma unroll
        for (int i = 0; i < 4; ++i) {
#pragma unroll
            for (int r = 0; r < 4; ++r) {
                const int row = wr + i * 16 + rq + r;
                const float v = acc[i][j][r] + bv;
                const float act = (q == 1) ? tanhf(v) : sigm(v);
                smem[row * 128 + col] = f2bf(act);
            }
        }
    }
    __syncthreads();

    // ---- epilogue 2: cell update, 16 elems/thread (row = t>>1, 16-col half)
    {
        const int row = t >> 1;
        const int hc  = (t & 1) * 16;
        const unsigned short* ex = smem + row * 128;
        s16x8 i0 = *(const s16x8*)(ex + hc);
        s16x8 i1 = *(const s16x8*)(ex + hc + 8);
        s16x8 g0 = *(const s16x8*)(ex + 32 + hc);
        s16x8 g1 = *(const s16x8*)(ex + 32 + hc + 8);
        s16x8 fg0 = *(const s16x8*)(ex + 64 + hc);
        s16x8 fg1 = *(const s16x8*)(ex + 64 + hc + 8);
        s16x8 o0 = *(const s16x8*)(ex + 96 + hc);
        s16x8 o1 = *(const s16x8*)(ex + 96 + hc + 8);

        const size_t gidx = (size_t)(m0 + row) * H_SZ + n0h + hc;
        float cn[16], hn[16];
#pragma unroll
        for (int k = 0; k < 16; ++k) {
            const float iv = bf2f((unsigned short)((k < 8 ? i0[k] : i1[k - 8])));
            const float gv = bf2f((unsigned short)((k < 8 ? g0[k] : g1[k - 8])));
            const float fv = bf2f((unsigned short)((k < 8 ? fg0[k] : fg1[k - 8])));
            const float ov = bf2f((unsigned short)((k < 8 ? o0[k] : o1[k - 8])));
            const float cv = a.cin[gidx + k];
            cn[k] = fv * cv + iv * gv;
            hn[k] = ov * cn[k];
        }
#pragma unroll
        for (int k = 0; k < 16; k += 4) {
            *(float4*)(a.c_out + gidx + k) = make_float4(cn[k], cn[k+1], cn[k+2], cn[k+3]);
            *(float4*)(a.h_out + gidx + k) = make_float4(hn[k], hn[k+1], hn[k+2], hn[k+3]);
            ushort4 hb;
            hb.x = f2bf(hn[k]);     hb.y = f2bf(hn[k+1]);
            hb.z = f2bf(hn[k+2]);   hb.w = f2bf(hn[k+3]);
            *(ushort4*)(a.HnB + gidx + k) = hb;
        }
    }
}

// ---------------- y GEMM: BK=128 core, f32 Wy direct (R6-measured) -------
__device__ __forceinline__ void gemm_bk128(
    const unsigned short* __restrict__ A,
    const float* __restrict__ W,
    int ld, int kLen, int m0, int n0,
    unsigned short* lA, unsigned short* lB,
    f32x4 acc[4][4], int t)
{
    const int lane = t & 63;
    const int w    = t >> 6;
    const int wr   = (w >> 1) << 6;
    const int wc   = (w & 1) << 6;
    const int lr   = lane & 15;
    const int q4   = lane >> 4;

    const int srow = t >> 4;                      // 0..15
    const int sblk = ((t & 15) ^ srow) << 3;      // swizzled col (elems)
    const unsigned short* gA = A + (size_t)(m0 + srow) * ld + sblk;
    const float*          gW = W + (size_t)(n0 + srow) * ld + sblk;
    const size_t st16 = (size_t)16 * ld;

    f32x4 f0[8], f1[8];
#pragma unroll
    for (int p = 0; p < 8; ++p) {
        const float* s = gW + p * st16;
        f0[p] = *(const f32x4*)(s);
        f1[p] = *(const f32x4*)(s + 4);
    }

    for (int k0 = 0; k0 < kLen; k0 += 128) {
#pragma unroll
        for (int p = 0; p < 8; ++p) {
            uint4 pk;
            pk.x = cvtpk(f0[p].x, f0[p].y);
            pk.y = cvtpk(f0[p].z, f0[p].w);
            pk.z = cvtpk(f1[p].x, f1[p].y);
            pk.w = cvtpk(f1[p].z, f1[p].w);
            *(uint4*)(lB + (t + 256 * p) * 8) = pk;
        }
#pragma unroll
        for (int p = 0; p < 8; ++p)
            gll(gA + k0 + p * st16, lA + (t + 256 * p) * 8);
        __syncthreads();

        if (k0 + 128 < kLen) {
#pragma unroll
            for (int p = 0; p < 8; ++p) {
                const float* s = gW + (k0 + 128) + p * st16;
                f0[p] = *(const f32x4*)(s);
                f1[p] = *(const f32x4*)(s + 4);
            }
        }

#pragma unroll
        for (int ks = 0; ks < 4; ++ks) {
            s16x8 af[4], bfr[4];
#pragma unroll
            for (int i = 0; i < 4; ++i) {
                const int ra = wr + i * 16 + lr;
                af[i] = *(const s16x8*)(lA + ra * 128 +
                         ((((ks << 2) + q4) ^ (ra & 15)) << 3));
            }
#pragma unroll
            for (int j = 0; j < 4; ++j) {
                const int rb = wc + j * 16 + lr;
                bfr[j] = *(const s16x8*)(lB + rb * 128 +
                          ((((ks << 2) + q4) ^ (rb & 15)) << 3));
            }
#pragma unroll
            for (int i = 0; i < 4; ++i)
#pragma unroll
                for (int j = 0; j < 4; ++j)
                    acc[i][j] = __builtin_amdgcn_mfma_f32_16x16x32_bf16(
                        af[i], bfr[j], acc[i][j], 0, 0, 0);
        }
        __syncthreads();
    }
}

__global__ __launch_bounds__(256, 2) void y_split_kernel(
    const unsigned short* __restrict__ Hn,
    const float* __restrict__ Wy,
    float* __restrict__ part)
{
    __shared__ unsigned short lA[128 * 128];
    __shared__ unsigned short lB[128 * 128];
    const int t   = threadIdx.x;
    const int b   = blockIdx.x;
    const int xcd = b & 7;
    const int i_  = b >> 3;                 // 0..31 within XCD
    const int ns  = xcd * 4 + (i_ >> 3);    // 0..31: (n-tile, split)
    const int m0  = (i_ & 7) * 128;
    const int n0  = (ns >> 2) * 128;
    const int s   = ns & 3;

    f32x4 acc[4][4] = {};
    gemm_bk128(Hn + s * 512, Wy + s * 512, H_SZ, 512, m0, n0, lA, lB, acc, t);

    const int lane = t & 63, w = t >> 6;
    const int wr = (w >> 1) << 6, wc = (w & 1) << 6;
    const int lr = lane & 15, rq = (lane >> 4) << 2;
    float* P = part + (size_t)s * B_SZ * E_SZ;
#pragma unroll
    for (int i = 0; i < 4; ++i) {
#pragma unroll
        for (int j = 0; j < 4; ++j) {
            const int n = n0 + wc + j * 16 + lr;
#pragma unroll
            for (int r = 0; r < 4; ++r) {
                const int m = m0 + wr + i * 16 + rq + r;
                P[(size_t)m * E_SZ + n] = acc[i][j][r];
            }
        }
    }
}

__global__ __launch_bounds__(256) void y_reduce_kernel(
    const float* __restrict__ part, const float* __restrict__ by,
    float* __restrict__ yout)
{
    const size_t BE = (size_t)B_SZ * E_SZ;
    const int idx = (blockIdx.x * 256 + threadIdx.x) * 4;
    float4 a = *(const float4*)(part + idx);
    float4 b2 = *(const float4*)(part + BE + idx);
    float4 c2 = *(const float4*)(part + 2 * BE + idx);
    float4 d2 = *(const float4*)(part + 3 * BE + idx);
    const int col = idx & (E_SZ - 1);
    float4 bv = *(const float4*)(by + col);
    float4 o;
    o.x = tanhf(a.x + b2.x + c2.x + d2.x + bv.x);
    o.y = tanhf(a.y + b2.y + c2.y + d2.y + bv.y);
    o.z = tanhf(a.z + b2.z + c2.z + d2.z + bv.z);
    o.w = tanhf(a.w + b2.w + c2.w + d2.w + bv.w);
    *(float4*)(yout + idx) = o;
}

// ---------------------------------------------------------------- launch
extern "C" void kernel_launch(void* const* d_in, const int* in_sizes, int n_in,
                              void* d_out, int out_size, void* d_ws, size_t ws_size,
                              hipStream_t stream) {
    const float* x   = (const float*)d_in[0];
    const float* c   = (const float*)d_in[1];
    const float* h   = (const float*)d_in[2];
    const float* Wxi = (const float*)d_in[3];
    const float* Whi = (const float*)d_in[4];
    const float* Bi  = (const float*)d_in[5];
    const float* Wxg = (const float*)d_in[6];
    const float* Whg = (const float*)d_in[7];
    const float* Bg  = (const float*)d_in[8];
    const float* Wxf = (const float*)d_in[9];
    const float* Whf = (const float*)d_in[10];
    const float* Bf  = (const float*)d_in[11];
    const float* Wxo = (const float*)d_in[12];
    const float* Who = (const float*)d_in[13];
    const float* Bo  = (const float*)d_in[14];
    const float* Why = (const float*)d_in[15];
    const float* By  = (const float*)d_in[16];

    const size_t BE = (size_t)B_SZ * E_SZ, BH = (size_t)B_SZ * H_SZ;
    const size_t HE = (size_t)H_SZ * E_SZ, HH = (size_t)H_SZ * H_SZ;

    unsigned short* ws  = (unsigned short*)d_ws;
    unsigned short* Xb  = ws;                 // BE bf16
    unsigned short* Hb  = Xb + BE;            // BH bf16
    unsigned short* Wxb = Hb + BH;            // 4*HE bf16
    unsigned short* Whb = Wxb + 4 * HE;       // 4*HH bf16
    unsigned short* HnB = Whb + 4 * HH;       // BH bf16
    float*          ypart = (float*)(HnB + BH); // 4*BE f32

    CastArgs ca;
    ca.src[0] = x;   ca.dst[0] = Xb;          ca.n[0] = (int)BE;
    ca.src[1] = h;   ca.dst[1] = Hb;          ca.n[1] = (int)BH;
    ca.src[2] = Wxi; ca.dst[2] = Wxb;         ca.n[2] = (int)HE;
    ca.src[3] = Wxg; ca.dst[3] = Wxb + HE;    ca.n[3] = (int)HE;
    ca.src[4] = Wxf; ca.dst[4] = Wxb + 2*HE;  ca.n[4] = (int)HE;
    ca.src[5] = Wxo; ca.dst[5] = Wxb + 3*HE;  ca.n[5] = (int)HE;
    ca.src[6] = Whi; ca.dst[6] = Whb;         ca.n[6] = (int)HH;
    ca.src[7] = Whg; ca.dst[7] = Whb + HH;    ca.n[7] = (int)HH;
    ca.src[8] = Whf; ca.dst[8] = Whb + 2*HH;  ca.n[8] = (int)HH;
    ca.src[9] = Who; ca.dst[9] = Whb + 3*HH;  ca.n[9] = (int)HH;
    hipLaunchKernelGGL(cast_kernel, dim3(512, 10), dim3(256), 0, stream, ca);

    float* y_out = (float*)d_out;
    float* c_out = y_out + BE;
    float* h_out = c_out + BH;

    GatesCellArgs ga;
    ga.Xb = Xb; ga.Hb = Hb; ga.Wxb = Wxb; ga.Whb = Whb;
    ga.bias[0] = Bi; ga.bias[1] = Bg; ga.bias[2] = Bf; ga.bias[3] = Bo;
    ga.cin = c; ga.c_out = c_out; ga.h_out = h_out; ga.HnB = HnB;
    hipLaunchKernelGGL(gates_cell_kernel, dim3(512), dim3(256), 0, stream, ga);

    hipLaunchKernelGGL(y_split_kernel, dim3(256), dim3(256), 0, stream,
                       HnB, Why, ypart);
    hipLaunchKernelGGL(y_reduce_kernel, dim3((unsigned)(BE / 1024)), dim3(256), 0, stream,
                       ypart, By, y_out);
}